// Round 1
// baseline (1462.341 us; speedup 1.0000x reference)
//
#include <hip/hip_runtime.h>
#include <math.h>

#define PI_D 3.14159265358979323846

// ---- problem constants ----
// B=2048, WIDTH=128, MODES=16, L=128

// ---- workspace float offsets ----
#define OFF_TW   0u                               // 128*32 twiddle matrix [l][c]; c<16: cos, c>=16: -sin
#define OFF_X0   4096u                            // 2048*128
#define OFF_WT   (OFF_X0 + 262144u)               // transposed spectral weights: 3 * (r,i) * [m][i][o]
#define OFF_XFR  (OFF_WT + 1572864u)              // 16*2048*128   (aliased as HPART later)
#define OFF_XFI  (OFF_XFR + 4194304u)
#define OFF_OFR  (OFF_XFI + 4194304u)
#define OFF_OFI  (OFF_OFR + 4194304u)
#define OFF_A    (OFF_OFI + 4194304u)             // 2048*128*128 activations
#define OFF_HP   OFF_XFR

__device__ __forceinline__ float gelu_f(float x) {
    return 0.5f * x * (1.0f + erff(x * 0.7071067811865476f));
}

// Fill twiddle matrix TW[l][c], 128x32: c<16 -> cos(2*pi*c*l/128), c>=16 -> -sin(2*pi*(c-16)*l/128)
__global__ void k_setup(float* ws) {
    int id = blockIdx.x * 256 + threadIdx.x;
    if (id < 4096) {
        int l = id >> 5, c = id & 31, m = c & 15;
        double ang = (PI_D / 64.0) * (double)((m * l) & 127);
        double v = (c < 16) ? cos(ang) : -sin(ang);
        ws[OFF_TW + id] = (float)v;
    }
}

// Transpose sc{1,2,3}_{wr,wi} from [i][o][m] to [m][i][o]
__global__ void k_transpose(const float* w1r, const float* w1i,
                            const float* w2r, const float* w2i,
                            const float* w3r, const float* w3i, float* ws) {
    int id = blockIdx.x * 256 + threadIdx.x;      // 3*262144 = 786432
    int lay = id >> 18;
    int rem = id & 262143;
    int m = rem >> 14, i = (rem >> 7) & 127, o = rem & 127;
    const float* sr = (lay == 0) ? w1r : (lay == 1) ? w2r : w3r;
    const float* si = (lay == 0) ? w1i : (lay == 1) ? w2i : w3i;
    int src = (i * 128 + o) * 16 + m;
    ws[OFF_WT + (unsigned)lay * 524288u + rem] = sr[src];
    ws[OFF_WT + (unsigned)lay * 524288u + 262144u + rem] = si[src];
}

// x0[b,c] = X1[b,:] . fc0_w[c,:] + fc0_b[c]
__global__ __launch_bounds__(256) void k_fc0(const float* X1, const float* w, const float* bias, float* ws) {
    __shared__ float xs[16][128];
    __shared__ float wsm[128][129];
    int t = threadIdx.x;
    int b0 = blockIdx.x * 16;
#pragma unroll
    for (int q = 0; q < 8; ++q) {
        int idx = q * 256 + t;
        xs[idx >> 7][idx & 127] = X1[b0 * 128 + idx];
    }
#pragma unroll
    for (int q = 0; q < 64; ++q) {
        int idx = q * 256 + t;
        wsm[idx >> 7][idx & 127] = w[idx];
    }
    __syncthreads();
    int c = t & 127, bh = t >> 7;
    float* x0 = ws + OFF_X0;
    for (int j = 0; j < 8; ++j) {
        int b = bh * 8 + j;
        float acc = bias[c];
#pragma unroll 8
        for (int k = 0; k < 128; ++k) acc += xs[b][k] * wsm[c][k];
        x0[(b0 + b) * 128 + c] = acc;
    }
}

// Layer 0: C_in = 1. DFT of x0 row, rank-1 mode mix with sc0, iDFT + rank-1 pointwise + gelu -> A
__global__ __launch_bounds__(256) void k_layer0(const float* w0r, const float* w0i,
                                                const float* w0w, const float* w0b, float* ws) {
    __shared__ float x0s[128];
    __shared__ float tws[128][33];
    __shared__ float xrs[16], xis[16];
    __shared__ __align__(16) float ors[2048];   // [o][m]
    __shared__ __align__(16) float ois[2048];
    int t = threadIdx.x, b = blockIdx.x;
    const float* tw = ws + OFF_TW;
    const float* x0 = ws + OFF_X0;
    if (t < 128) x0s[t] = x0[b * 128 + t];
#pragma unroll
    for (int q = 0; q < 16; ++q) {
        int idx = q * 256 + t;
        tws[idx >> 5][idx & 31] = tw[idx];
    }
    __syncthreads();
    if (t < 32) {
        float acc = 0.f;
        for (int l = 0; l < 128; ++l) acc += x0s[l] * tws[l][t];
        if (t < 16) xrs[t] = acc; else xis[t - 16] = acc;
    }
    __syncthreads();
#pragma unroll
    for (int q = 0; q < 8; ++q) {
        int idx = q * 256 + t;      // idx = o*16 + m
        int m = idx & 15;
        float wr = w0r[idx], wi = w0i[idx];
        float sc = (m == 0) ? (1.f / 128.f) : (2.f / 128.f);
        float xr = xrs[m], xi = xis[m];
        ors[idx] = (xr * wr - xi * wi) * sc;
        ois[idx] = (xr * wi + xi * wr) * sc;
    }
    __syncthreads();
    int l = t & 127, og = t >> 7;
    float tvc[16], tvs[16];
#pragma unroll
    for (int m = 0; m < 16; ++m) { tvc[m] = tws[l][m]; tvs[m] = tws[l][16 + m]; }
    float xl = x0s[l];
    float* A = ws + OFF_A + b * 16384;
    const float4* or4 = (const float4*)ors;
    const float4* oi4 = (const float4*)ois;
    for (int oj = 0; oj < 64; ++oj) {
        int o = og * 64 + oj;
        float acc = xl * w0w[o] + w0b[o];
#pragma unroll
        for (int q = 0; q < 4; ++q) {
            float4 r4 = or4[o * 4 + q];
            float4 i4 = oi4[o * 4 + q];
            acc += r4.x * tvc[4 * q + 0] + i4.x * tvs[4 * q + 0];
            acc += r4.y * tvc[4 * q + 1] + i4.y * tvs[4 * q + 1];
            acc += r4.z * tvc[4 * q + 2] + i4.z * tvs[4 * q + 2];
            acc += r4.w * tvc[4 * q + 3] + i4.w * tvs[4 * q + 3];
        }
        A[o * 128 + l] = gelu_f(acc);
    }
}

// DFT GEMM: rows (b*128+i) of A times TW[128][32] -> xfr[m][row], xfi[m][row]
__global__ __launch_bounds__(256) void k_dft(float* ws) {
    __shared__ float as_[256][33];
    __shared__ float tws[32][32];
    int t = threadIdx.x;
    int row0 = blockIdx.x * 256;
    const float* A = ws + OFF_A;
    const float* tw = ws + OFF_TW;
    float acc[8][4];
#pragma unroll
    for (int j = 0; j < 8; ++j)
#pragma unroll
        for (int cc = 0; cc < 4; ++cc) acc[j][cc] = 0.f;
    int tr = t >> 3, tc = t & 7;
    for (int kc = 0; kc < 4; ++kc) {
        int k0 = kc * 32;
        __syncthreads();
#pragma unroll
        for (int q = 0; q < 32; ++q) {
            int idx = q * 256 + t;
            as_[idx >> 5][idx & 31] = A[(row0 + (idx >> 5)) * 128 + k0 + (idx & 31)];
        }
#pragma unroll
        for (int q = 0; q < 4; ++q) {
            int idx = q * 256 + t;
            tws[idx >> 5][idx & 31] = tw[(k0 + (idx >> 5)) * 32 + (idx & 31)];
        }
        __syncthreads();
#pragma unroll 4
        for (int kk = 0; kk < 32; ++kk) {
            float av[8], tv[4];
#pragma unroll
            for (int j = 0; j < 8; ++j) av[j] = as_[tr * 8 + j][kk];
#pragma unroll
            for (int cc = 0; cc < 4; ++cc) tv[cc] = tws[kk][tc + 8 * cc];
#pragma unroll
            for (int j = 0; j < 8; ++j)
#pragma unroll
                for (int cc = 0; cc < 4; ++cc) acc[j][cc] += av[j] * tv[cc];
        }
    }
    float* xfr = ws + OFF_XFR;
    float* xfi = ws + OFF_XFI;
#pragma unroll
    for (int cc = 0; cc < 4; ++cc) {
        int c = tc + 8 * cc;
        float* dst = (c < 16) ? (xfr + c * 262144) : (xfi + (c - 16) * 262144);
#pragma unroll
        for (int j = 0; j < 8; ++j) dst[row0 + tr * 8 + j] = acc[j][cc];
    }
}

// Per-mode complex GEMM: of[b,o] = sum_i xf[b,i] * w[i,o]
__global__ __launch_bounds__(256) void k_modemix(int lay, float* ws) {
    __shared__ float xrs[64][33], xis[64][33];
    __shared__ float wrs[32][128], wis[32][128];
    int t = threadIdx.x;
    int b0 = blockIdx.x * 64;
    int m = blockIdx.y;
    const float* xfr = ws + OFF_XFR + m * 262144;
    const float* xfi = ws + OFF_XFI + m * 262144;
    const float* wtr = ws + OFF_WT + (unsigned)lay * 524288u + m * 16384;
    const float* wti = wtr + 262144;
    int tb = t >> 4, tc = t & 15;
    float accr[4][8], acci[4][8];
#pragma unroll
    for (int jb = 0; jb < 4; ++jb)
#pragma unroll
        for (int jc = 0; jc < 8; ++jc) { accr[jb][jc] = 0.f; acci[jb][jc] = 0.f; }
    for (int kc = 0; kc < 4; ++kc) {
        int k0 = kc * 32;
        __syncthreads();
#pragma unroll
        for (int q = 0; q < 8; ++q) {
            int idx = q * 256 + t;
            int r = idx >> 5, kk = idx & 31;
            xrs[r][kk] = xfr[(b0 + r) * 128 + k0 + kk];
            xis[r][kk] = xfi[(b0 + r) * 128 + k0 + kk];
        }
#pragma unroll
        for (int q = 0; q < 16; ++q) {
            int idx = q * 256 + t;
            int kk = idx >> 7, o = idx & 127;
            wrs[kk][o] = wtr[(k0 + kk) * 128 + o];
            wis[kk][o] = wti[(k0 + kk) * 128 + o];
        }
        __syncthreads();
#pragma unroll 4
        for (int kk = 0; kk < 32; ++kk) {
            float xrv[4], xiv[4], wrv[8], wiv[8];
#pragma unroll
            for (int jb = 0; jb < 4; ++jb) { xrv[jb] = xrs[tb * 4 + jb][kk]; xiv[jb] = xis[tb * 4 + jb][kk]; }
#pragma unroll
            for (int jc = 0; jc < 8; ++jc) { wrv[jc] = wrs[kk][tc + 16 * jc]; wiv[jc] = wis[kk][tc + 16 * jc]; }
#pragma unroll
            for (int jb = 0; jb < 4; ++jb)
#pragma unroll
                for (int jc = 0; jc < 8; ++jc) {
                    accr[jb][jc] += xrv[jb] * wrv[jc] - xiv[jb] * wiv[jc];
                    acci[jb][jc] += xrv[jb] * wiv[jc] + xiv[jb] * wrv[jc];
                }
        }
    }
    float* ofr = ws + OFF_OFR + m * 262144;
    float* ofi = ws + OFF_OFI + m * 262144;
#pragma unroll
    for (int jb = 0; jb < 4; ++jb) {
        int b = b0 + tb * 4 + jb;
#pragma unroll
        for (int jc = 0; jc < 8; ++jc) {
            int o = tc + 16 * jc;
            ofr[b * 128 + o] = accr[jb][jc];
            ofi[b * 128 + o] = acci[jb][jc];
        }
    }
}

// iDFT + pointwise + bias (+gelu), in-place over A. One block per batch b.
template <int GELU>
__global__ __launch_bounds__(256) void k_layerB(const float* pw_w, const float* pw_b, float* ws) {
    __shared__ float ofr_s[16][128], ofi_s[16][128];
    __shared__ float tws[128][33];
    __shared__ float as_[32][128];
    __shared__ float ws_[128][33];
    int t = threadIdx.x, b = blockIdx.x;
    const float* tw = ws + OFF_TW;
    float* A = ws + OFF_A + b * 16384;
    const float* ofr = ws + OFF_OFR;
    const float* ofi = ws + OFF_OFI;
#pragma unroll
    for (int q = 0; q < 8; ++q) {
        int idx = q * 256 + t;
        int mm = idx >> 7, o = idx & 127;
        float sc = (mm == 0) ? (1.f / 128.f) : (2.f / 128.f);
        ofr_s[mm][o] = ofr[mm * 262144 + b * 128 + o] * sc;
        ofi_s[mm][o] = ofi[mm * 262144 + b * 128 + o] * sc;
    }
#pragma unroll
    for (int q = 0; q < 16; ++q) {
        int idx = q * 256 + t;
        tws[idx >> 5][idx & 31] = tw[idx];
    }
    int ty = t >> 4, tx = t & 15;
    float acc[8][8];
#pragma unroll
    for (int jo = 0; jo < 8; ++jo)
#pragma unroll
        for (int jl = 0; jl < 8; ++jl) acc[jo][jl] = 0.f;
    for (int ch = 0; ch < 4; ++ch) {
        int i0 = ch * 32;
        __syncthreads();
#pragma unroll
        for (int q = 0; q < 16; ++q) {
            int idx = q * 256 + t;
            as_[idx >> 7][idx & 127] = A[(i0 + (idx >> 7)) * 128 + (idx & 127)];
        }
#pragma unroll
        for (int q = 0; q < 16; ++q) {
            int idx = q * 256 + t;
            int o = idx >> 5, ic = idx & 31;
            ws_[o][ic] = pw_w[o * 128 + i0 + ic];
        }
        __syncthreads();
#pragma unroll 4
        for (int ic = 0; ic < 32; ++ic) {
            float av[8], wv[8];
#pragma unroll
            for (int jl = 0; jl < 8; ++jl) av[jl] = as_[ic][tx + 16 * jl];
#pragma unroll
            for (int jo = 0; jo < 8; ++jo) wv[jo] = ws_[ty * 8 + jo][ic];
#pragma unroll
            for (int jo = 0; jo < 8; ++jo)
#pragma unroll
                for (int jl = 0; jl < 8; ++jl) acc[jo][jl] += wv[jo] * av[jl];
        }
    }
    // iDFT epilogue
#pragma unroll 2
    for (int m = 0; m < 16; ++m) {
        float orv[8], oiv[8];
#pragma unroll
        for (int jo = 0; jo < 8; ++jo) { orv[jo] = ofr_s[m][ty * 8 + jo]; oiv[jo] = ofi_s[m][ty * 8 + jo]; }
#pragma unroll
        for (int jl = 0; jl < 8; ++jl) {
            int l = tx + 16 * jl;
            float cv = tws[l][m], sv = tws[l][16 + m];
#pragma unroll
            for (int jo = 0; jo < 8; ++jo) acc[jo][jl] += orv[jo] * cv + oiv[jo] * sv;
        }
    }
#pragma unroll
    for (int jo = 0; jo < 8; ++jo) {
        int o = ty * 8 + jo;
        float bv = pw_b[o];
#pragma unroll
        for (int jl = 0; jl < 8; ++jl) {
            float v = acc[jo][jl] + bv;
            if (GELU) v = gelu_f(v);
            A[o * 128 + tx + 16 * jl] = v;
        }
    }
}

// fc1 with split-K: hpart[kz][b][c] = sum_{k in chunk} A[b][k] * fc1_w[c][k]
__global__ __launch_bounds__(256) void k_fc12(const float* fc1w, float* ws) {
    __shared__ float as_[64][33];
    __shared__ float ws_[32][129];
    int t = threadIdx.x;
    int b0 = blockIdx.x * 64;
    int kz = blockIdx.y;
    const float* A = ws + OFF_A;
    int tb = t >> 4, tc = t & 15;
    float acc[4][8];
#pragma unroll
    for (int jb = 0; jb < 4; ++jb)
#pragma unroll
        for (int jc = 0; jc < 8; ++jc) acc[jb][jc] = 0.f;
    for (int ks = 0; ks < 32; ++ks) {
        int k0 = kz * 1024 + ks * 32;
        __syncthreads();
#pragma unroll
        for (int q = 0; q < 8; ++q) {
            int idx = q * 256 + t;
            as_[idx >> 5][idx & 31] = A[(b0 + (idx >> 5)) * 16384 + k0 + (idx & 31)];
        }
#pragma unroll
        for (int q = 0; q < 16; ++q) {
            int idx = q * 256 + t;
            int c = idx >> 5, kk = idx & 31;
            ws_[kk][c] = fc1w[c * 16384 + k0 + kk];
        }
        __syncthreads();
#pragma unroll 4
        for (int kk = 0; kk < 32; ++kk) {
            float av[4], wv[8];
#pragma unroll
            for (int jb = 0; jb < 4; ++jb) av[jb] = as_[tb * 4 + jb][kk];
#pragma unroll
            for (int jc = 0; jc < 8; ++jc) wv[jc] = ws_[kk][tc + 16 * jc];
#pragma unroll
            for (int jb = 0; jb < 4; ++jb)
#pragma unroll
                for (int jc = 0; jc < 8; ++jc) acc[jb][jc] += av[jb] * wv[jc];
        }
    }
    float* hp = ws + OFF_HP + kz * 262144;
#pragma unroll
    for (int jb = 0; jb < 4; ++jb)
#pragma unroll
        for (int jc = 0; jc < 8; ++jc)
            hp[(b0 + tb * 4 + jb) * 128 + tc + 16 * jc] = acc[jb][jc];
}

// reduce split-K partials + fc1 bias + gelu, then fc2
__global__ __launch_bounds__(256) void k_fc2(const float* fc1b, const float* fc2w, const float* fc2b,
                                             float* ws, float* out) {
    __shared__ float hs[8][128];
    __shared__ float w2s[64][129];
    int t = threadIdx.x;
    int b0 = blockIdx.x * 8;
    const float* hp = ws + OFF_HP;
#pragma unroll
    for (int q = 0; q < 4; ++q) {
        int idx = q * 256 + t;
        int bb = idx >> 7, c = idx & 127;
        float s = fc1b[c];
#pragma unroll
        for (int kz = 0; kz < 16; ++kz) s += hp[kz * 262144 + (b0 + bb) * 128 + c];
        hs[bb][c] = gelu_f(s);
    }
#pragma unroll
    for (int q = 0; q < 32; ++q) {
        int idx = q * 256 + t;
        w2s[idx >> 7][idx & 127] = fc2w[idx];
    }
    __syncthreads();
#pragma unroll
    for (int q = 0; q < 2; ++q) {
        int idx = q * 256 + t;
        int bb = idx >> 6, u = idx & 63;
        float acc = fc2b[u];
#pragma unroll 8
        for (int c = 0; c < 128; ++c) acc += hs[bb][c] * w2s[u][c];
        out[(b0 + bb) * 64 + u] = acc;
    }
}

extern "C" void kernel_launch(void* const* d_in, const int* in_sizes, int n_in,
                              void* d_out, int out_size, void* d_ws, size_t ws_size,
                              hipStream_t stream) {
    const float* X1   = (const float*)d_in[0];
    const float* fc0w = (const float*)d_in[1];
    const float* fc0b = (const float*)d_in[2];
    const float* s0r  = (const float*)d_in[3];
    const float* s0i  = (const float*)d_in[4];
    const float* s1r  = (const float*)d_in[5];
    const float* s1i  = (const float*)d_in[6];
    const float* s2r  = (const float*)d_in[7];
    const float* s2i  = (const float*)d_in[8];
    const float* s3r  = (const float*)d_in[9];
    const float* s3i  = (const float*)d_in[10];
    const float* w0w  = (const float*)d_in[11];
    const float* w0b  = (const float*)d_in[12];
    const float* w1w  = (const float*)d_in[13];
    const float* w1b  = (const float*)d_in[14];
    const float* w2w  = (const float*)d_in[15];
    const float* w2b  = (const float*)d_in[16];
    const float* w3w  = (const float*)d_in[17];
    const float* w3b  = (const float*)d_in[18];
    const float* fc1w = (const float*)d_in[19];
    const float* fc1b = (const float*)d_in[20];
    const float* fc2w = (const float*)d_in[21];
    const float* fc2b = (const float*)d_in[22];
    float* ws  = (float*)d_ws;
    float* out = (float*)d_out;

    k_setup<<<dim3(16), dim3(256), 0, stream>>>(ws);
    k_transpose<<<dim3(3072), dim3(256), 0, stream>>>(s1r, s1i, s2r, s2i, s3r, s3i, ws);
    k_fc0<<<dim3(128), dim3(256), 0, stream>>>(X1, fc0w, fc0b, ws);
    k_layer0<<<dim3(2048), dim3(256), 0, stream>>>(s0r, s0i, w0w, w0b, ws);

    const float* pww[3] = {w1w, w2w, w3w};
    const float* pwb[3] = {w1b, w2b, w3b};
    for (int lay = 0; lay < 3; ++lay) {
        k_dft<<<dim3(1024), dim3(256), 0, stream>>>(ws);
        k_modemix<<<dim3(32, 16), dim3(256), 0, stream>>>(lay, ws);
        if (lay < 2)
            k_layerB<1><<<dim3(2048), dim3(256), 0, stream>>>(pww[lay], pwb[lay], ws);
        else
            k_layerB<0><<<dim3(2048), dim3(256), 0, stream>>>(pww[lay], pwb[lay], ws);
    }

    k_fc12<<<dim3(32, 16), dim3(256), 0, stream>>>(fc1w, ws);
    k_fc2<<<dim3(256), dim3(256), 0, stream>>>(fc1b, fc2w, fc2b, ws, out);
}

// Round 4
// 1094.015 us; speedup vs baseline: 1.3367x; 1.3367x over previous
//
#include <hip/hip_runtime.h>
#include <math.h>

#define PI_D 3.14159265358979323846

// ---- workspace float offsets ----
#define OFF_TW   0u
#define OFF_X0   4096u
#define OFF_WT   (OFF_X0 + 262144u)
#define OFF_XFR  (OFF_WT + 1572864u)
#define OFF_XFI  (OFF_XFR + 4194304u)
#define OFF_OFR  (OFF_XFI + 4194304u)
#define OFF_OFI  (OFF_OFR + 4194304u)
#define OFF_A    (OFF_OFI + 4194304u)
#define OFF_HP   OFF_XFR                          // 64 * 262144 floats, exactly spans XFR..A

__device__ __forceinline__ float gelu_f(float x) {
    return 0.5f * x * (1.0f + erff(x * 0.7071067811865476f));
}

__global__ void k_setup(float* ws) {
    int id = blockIdx.x * 256 + threadIdx.x;
    if (id < 4096) {
        int l = id >> 5, c = id & 31, m = c & 15;
        double ang = (PI_D / 64.0) * (double)((m * l) & 127);
        double v = (c < 16) ? cos(ang) : -sin(ang);
        ws[OFF_TW + id] = (float)v;
    }
}

__global__ void k_transpose(const float* w1r, const float* w1i,
                            const float* w2r, const float* w2i,
                            const float* w3r, const float* w3i, float* ws) {
    int id = blockIdx.x * 256 + threadIdx.x;
    int lay = id >> 18;
    int rem = id & 262143;
    int m = rem >> 14, i = (rem >> 7) & 127, o = rem & 127;
    const float* sr = (lay == 0) ? w1r : (lay == 1) ? w2r : w3r;
    const float* si = (lay == 0) ? w1i : (lay == 1) ? w2i : w3i;
    int src = (i * 128 + o) * 16 + m;
    ws[OFF_WT + (unsigned)lay * 524288u + rem] = sr[src];
    ws[OFF_WT + (unsigned)lay * 524288u + 262144u + rem] = si[src];
}

__global__ __launch_bounds__(256) void k_fc0(const float* X1, const float* w, const float* bias, float* ws) {
    __shared__ float xs[16][128];
    __shared__ float wsm[128][129];
    int t = threadIdx.x;
    int b0 = blockIdx.x * 16;
#pragma unroll
    for (int q = 0; q < 8; ++q) {
        int idx = q * 256 + t;
        xs[idx >> 7][idx & 127] = X1[b0 * 128 + idx];
    }
#pragma unroll
    for (int q = 0; q < 64; ++q) {
        int idx = q * 256 + t;
        wsm[idx >> 7][idx & 127] = w[idx];
    }
    __syncthreads();
    int c = t & 127, bh = t >> 7;
    float* x0 = ws + OFF_X0;
    for (int j = 0; j < 8; ++j) {
        int b = bh * 8 + j;
        float acc = bias[c];
#pragma unroll 8
        for (int k = 0; k < 128; ++k) acc += xs[b][k] * wsm[c][k];
        x0[(b0 + b) * 128 + c] = acc;
    }
}

__global__ __launch_bounds__(256) void k_layer0(const float* w0r, const float* w0i,
                                                const float* w0w, const float* w0b, float* ws) {
    __shared__ float x0s[128];
    __shared__ float tws[128][33];
    __shared__ float xrs[16], xis[16];
    __shared__ __align__(16) float ors[2048];
    __shared__ __align__(16) float ois[2048];
    int t = threadIdx.x, b = blockIdx.x;
    const float* tw = ws + OFF_TW;
    const float* x0 = ws + OFF_X0;
    if (t < 128) x0s[t] = x0[b * 128 + t];
#pragma unroll
    for (int q = 0; q < 16; ++q) {
        int idx = q * 256 + t;
        tws[idx >> 5][idx & 31] = tw[idx];
    }
    __syncthreads();
    if (t < 32) {
        float acc = 0.f;
        for (int l = 0; l < 128; ++l) acc += x0s[l] * tws[l][t];
        if (t < 16) xrs[t] = acc; else xis[t - 16] = acc;
    }
    __syncthreads();
#pragma unroll
    for (int q = 0; q < 8; ++q) {
        int idx = q * 256 + t;
        int m = idx & 15;
        float wr = w0r[idx], wi = w0i[idx];
        float sc = (m == 0) ? (1.f / 128.f) : (2.f / 128.f);
        float xr = xrs[m], xi = xis[m];
        ors[idx] = (xr * wr - xi * wi) * sc;
        ois[idx] = (xr * wi + xi * wr) * sc;
    }
    __syncthreads();
    int l = t & 127, og = t >> 7;
    float tvc[16], tvs[16];
#pragma unroll
    for (int m = 0; m < 16; ++m) { tvc[m] = tws[l][m]; tvs[m] = tws[l][16 + m]; }
    float xl = x0s[l];
    float* A = ws + OFF_A + b * 16384;
    const float4* or4 = (const float4*)ors;
    const float4* oi4 = (const float4*)ois;
    for (int oj = 0; oj < 64; ++oj) {
        int o = og * 64 + oj;
        float acc = xl * w0w[o] + w0b[o];
#pragma unroll
        for (int q = 0; q < 4; ++q) {
            float4 r4 = or4[o * 4 + q];
            float4 i4 = oi4[o * 4 + q];
            acc += r4.x * tvc[4 * q + 0] + i4.x * tvs[4 * q + 0];
            acc += r4.y * tvc[4 * q + 1] + i4.y * tvs[4 * q + 1];
            acc += r4.z * tvc[4 * q + 2] + i4.z * tvs[4 * q + 2];
            acc += r4.w * tvc[4 * q + 3] + i4.w * tvs[4 * q + 3];
        }
        A[o * 128 + l] = gelu_f(acc);
    }
}

// DFT GEMM: 512 rows x 32 cols per block, 8x8 per thread, float4 LDS reads.
__global__ __launch_bounds__(256) void k_dft(float* ws) {
    __shared__ float as_[16][516];
    __shared__ float tws_[16][32];
    int t = threadIdx.x;
    int row0 = blockIdx.x * 512;
    const float* A = ws + OFF_A;
    const float* tw = ws + OFF_TW;
    int tr = t >> 2, tc = t & 3;          // 64 row-groups x 4 col-groups
    float acc[8][8];
#pragma unroll
    for (int j = 0; j < 8; ++j)
#pragma unroll
        for (int cc = 0; cc < 8; ++cc) acc[j][cc] = 0.f;
    for (int kc = 0; kc < 8; ++kc) {
        int k0 = kc * 16;
        __syncthreads();
#pragma unroll
        for (int q = 0; q < 8; ++q) {
            int idx = q * 256 + t;
            int r = idx >> 2, kq = idx & 3;
            float4 v = *(const float4*)&A[(row0 + r) * 128 + k0 + 4 * kq];
            as_[4 * kq + 0][r] = v.x; as_[4 * kq + 1][r] = v.y;
            as_[4 * kq + 2][r] = v.z; as_[4 * kq + 3][r] = v.w;
        }
#pragma unroll
        for (int q = 0; q < 2; ++q) {           // FIX: 512 elements need 2x256
            int idx = q * 256 + t;
            tws_[idx >> 5][idx & 31] = tw[(k0 + (idx >> 5)) * 32 + (idx & 31)];
        }
        __syncthreads();
#pragma unroll 8
        for (int kk = 0; kk < 16; ++kk) {
            float4 a0 = *(const float4*)&as_[kk][tr * 8];
            float4 a1 = *(const float4*)&as_[kk][tr * 8 + 4];
            float4 t0 = *(const float4*)&tws_[kk][tc * 8];
            float4 t1 = *(const float4*)&tws_[kk][tc * 8 + 4];
            float av[8] = {a0.x,a0.y,a0.z,a0.w,a1.x,a1.y,a1.z,a1.w};
            float tv[8] = {t0.x,t0.y,t0.z,t0.w,t1.x,t1.y,t1.z,t1.w};
#pragma unroll
            for (int j = 0; j < 8; ++j)
#pragma unroll
                for (int cc = 0; cc < 8; ++cc) acc[j][cc] += av[j] * tv[cc];
        }
    }
    float* xfr = ws + OFF_XFR;
    float* xfi = ws + OFF_XFI;
#pragma unroll
    for (int cc = 0; cc < 8; ++cc) {
        int c = tc * 8 + cc;
        float* dst = (c < 16) ? (xfr + c * 262144) : (xfi + (c - 16) * 262144);
        float4 v0 = make_float4(acc[0][cc], acc[1][cc], acc[2][cc], acc[3][cc]);
        float4 v1 = make_float4(acc[4][cc], acc[5][cc], acc[6][cc], acc[7][cc]);
        *(float4*)&dst[row0 + tr * 8] = v0;
        *(float4*)&dst[row0 + tr * 8 + 4] = v1;
    }
}

// Per-mode complex GEMM: 64 batch rows x 128 out, 4x8 complex per thread.
__global__ __launch_bounds__(256) void k_modemix(int lay, float* ws) {
    __shared__ float xrs[32][68], xis[32][68];
    __shared__ float wrs[32][128], wis[32][128];
    int t = threadIdx.x;
    int b0 = blockIdx.x * 64;
    int m = blockIdx.y;
    const float* xfr = ws + OFF_XFR + m * 262144;
    const float* xfi = ws + OFF_XFI + m * 262144;
    const float* wtr = ws + OFF_WT + (unsigned)lay * 524288u + m * 16384;
    const float* wti = wtr + 262144;
    int tb = t >> 4, tc = t & 15;
    float accr[4][8], acci[4][8];
#pragma unroll
    for (int jb = 0; jb < 4; ++jb)
#pragma unroll
        for (int jc = 0; jc < 8; ++jc) { accr[jb][jc] = 0.f; acci[jb][jc] = 0.f; }
    for (int kc = 0; kc < 4; ++kc) {
        int k0 = kc * 32;
        __syncthreads();
#pragma unroll
        for (int q = 0; q < 2; ++q) {
            int idx = q * 256 + t;
            int r = idx >> 3, kq = idx & 7;
            float4 vr = *(const float4*)&xfr[(b0 + r) * 128 + k0 + 4 * kq];
            float4 vi = *(const float4*)&xfi[(b0 + r) * 128 + k0 + 4 * kq];
            xrs[4*kq+0][r] = vr.x; xrs[4*kq+1][r] = vr.y; xrs[4*kq+2][r] = vr.z; xrs[4*kq+3][r] = vr.w;
            xis[4*kq+0][r] = vi.x; xis[4*kq+1][r] = vi.y; xis[4*kq+2][r] = vi.z; xis[4*kq+3][r] = vi.w;
        }
#pragma unroll
        for (int q = 0; q < 4; ++q) {
            int idx = q * 256 + t;
            int kk = idx >> 5, oq = idx & 31;
            *(float4*)&wrs[kk][4*oq] = *(const float4*)&wtr[(k0 + kk) * 128 + 4*oq];
            *(float4*)&wis[kk][4*oq] = *(const float4*)&wti[(k0 + kk) * 128 + 4*oq];
        }
        __syncthreads();
#pragma unroll 4
        for (int kk = 0; kk < 32; ++kk) {
            float4 xr4 = *(const float4*)&xrs[kk][tb * 4];
            float4 xi4 = *(const float4*)&xis[kk][tb * 4];
            float4 wr0 = *(const float4*)&wrs[kk][tc * 8];
            float4 wr1 = *(const float4*)&wrs[kk][tc * 8 + 4];
            float4 wi0 = *(const float4*)&wis[kk][tc * 8];
            float4 wi1 = *(const float4*)&wis[kk][tc * 8 + 4];
            float xrv[4] = {xr4.x, xr4.y, xr4.z, xr4.w};
            float xiv[4] = {xi4.x, xi4.y, xi4.z, xi4.w};
            float wrv[8] = {wr0.x,wr0.y,wr0.z,wr0.w,wr1.x,wr1.y,wr1.z,wr1.w};
            float wiv[8] = {wi0.x,wi0.y,wi0.z,wi0.w,wi1.x,wi1.y,wi1.z,wi1.w};
#pragma unroll
            for (int jb = 0; jb < 4; ++jb)
#pragma unroll
                for (int jc = 0; jc < 8; ++jc) {
                    accr[jb][jc] += xrv[jb] * wrv[jc] - xiv[jb] * wiv[jc];
                    acci[jb][jc] += xrv[jb] * wiv[jc] + xiv[jb] * wrv[jc];
                }
        }
    }
    float* ofr = ws + OFF_OFR + m * 262144;
    float* ofi = ws + OFF_OFI + m * 262144;
#pragma unroll
    for (int jb = 0; jb < 4; ++jb) {
        int b = b0 + tb * 4 + jb;
        float4 r0 = make_float4(accr[jb][0], accr[jb][1], accr[jb][2], accr[jb][3]);
        float4 r1 = make_float4(accr[jb][4], accr[jb][5], accr[jb][6], accr[jb][7]);
        float4 i0 = make_float4(acci[jb][0], acci[jb][1], acci[jb][2], acci[jb][3]);
        float4 i1 = make_float4(acci[jb][4], acci[jb][5], acci[jb][6], acci[jb][7]);
        *(float4*)&ofr[b * 128 + tc * 8]     = r0;
        *(float4*)&ofr[b * 128 + tc * 8 + 4] = r1;
        *(float4*)&ofi[b * 128 + tc * 8]     = i0;
        *(float4*)&ofi[b * 128 + tc * 8 + 4] = i1;
    }
}

// iDFT + pointwise + bias (+gelu), in-place over A. One block per batch b.
// l-contiguous per-thread columns: all LDS reads and global stores are float4.
template <int GELU>
__global__ __launch_bounds__(256) void k_layerB(const float* pw_w, const float* pw_b, float* ws) {
    __shared__ float ofr_s[16][128], ofi_s[16][128];
    __shared__ float as_[32][128];
    __shared__ float wsx[32][132];                 // main: W^T tile; epilogue: aliased as tws[128][33]
    int t = threadIdx.x, b = blockIdx.x;
    const float* tw = ws + OFF_TW;
    float* A = ws + OFF_A + b * 16384;
    const float* ofr = ws + OFF_OFR;
    const float* ofi = ws + OFF_OFI;
    int ty = t >> 4, tx = t & 15;                  // o = ty*8+jo, l = tx*8+jl
    float bv[8];
#pragma unroll
    for (int jo = 0; jo < 8; ++jo) bv[jo] = pw_b[ty * 8 + jo];
#pragma unroll
    for (int q = 0; q < 2; ++q) {
        int idx = q * 256 + t;
        int mm = idx >> 5, oq = idx & 31;
        float sc = (mm == 0) ? (1.f / 128.f) : (2.f / 128.f);
        float4 vr = *(const float4*)&ofr[mm * 262144 + b * 128 + 4 * oq];
        float4 vi = *(const float4*)&ofi[mm * 262144 + b * 128 + 4 * oq];
        vr.x *= sc; vr.y *= sc; vr.z *= sc; vr.w *= sc;
        vi.x *= sc; vi.y *= sc; vi.z *= sc; vi.w *= sc;
        *(float4*)&ofr_s[mm][4 * oq] = vr;
        *(float4*)&ofi_s[mm][4 * oq] = vi;
    }
    float acc[8][8];
#pragma unroll
    for (int jo = 0; jo < 8; ++jo)
#pragma unroll
        for (int jl = 0; jl < 8; ++jl) acc[jo][jl] = 0.f;
    for (int ch = 0; ch < 4; ++ch) {
        int i0 = ch * 32;
        __syncthreads();
#pragma unroll
        for (int q = 0; q < 4; ++q) {
            int idx = q * 256 + t;
            int ic = idx >> 5, lq = idx & 31;
            *(float4*)&as_[ic][4 * lq] = *(const float4*)&A[(i0 + ic) * 128 + 4 * lq];
        }
#pragma unroll
        for (int q = 0; q < 4; ++q) {
            int idx = q * 256 + t;
            int o = idx >> 3, iq = idx & 7;
            float4 v = *(const float4*)&pw_w[o * 128 + i0 + 4 * iq];
            wsx[4*iq+0][o] = v.x; wsx[4*iq+1][o] = v.y; wsx[4*iq+2][o] = v.z; wsx[4*iq+3][o] = v.w;
        }
        __syncthreads();
#pragma unroll 4
        for (int ic = 0; ic < 32; ++ic) {
            float4 a0 = *(const float4*)&as_[ic][tx * 8];
            float4 a1 = *(const float4*)&as_[ic][tx * 8 + 4];
            float4 w0 = *(const float4*)&wsx[ic][ty * 8];
            float4 w1 = *(const float4*)&wsx[ic][ty * 8 + 4];
            float av[8] = {a0.x,a0.y,a0.z,a0.w,a1.x,a1.y,a1.z,a1.w};
            float wv[8] = {w0.x,w0.y,w0.z,w0.w,w1.x,w1.y,w1.z,w1.w};
#pragma unroll
            for (int jo = 0; jo < 8; ++jo)
#pragma unroll
                for (int jl = 0; jl < 8; ++jl) acc[jo][jl] += wv[jo] * av[jl];
        }
    }
    __syncthreads();
    // reload twiddles into wsx region, aliased [128][33]
    float (*twsA)[33] = (float(*)[33])wsx;
#pragma unroll
    for (int q = 0; q < 4; ++q) {
        int idx = q * 256 + t;
        int l = idx >> 3, cq = idx & 7;
        float4 v = *(const float4*)&tw[l * 32 + 4 * cq];
        twsA[l][4*cq+0] = v.x; twsA[l][4*cq+1] = v.y; twsA[l][4*cq+2] = v.z; twsA[l][4*cq+3] = v.w;
    }
    __syncthreads();
#pragma unroll 2
    for (int m = 0; m < 16; ++m) {
        float orv[8], oiv[8];
#pragma unroll
        for (int jo = 0; jo < 8; ++jo) { orv[jo] = ofr_s[m][ty * 8 + jo]; oiv[jo] = ofi_s[m][ty * 8 + jo]; }
        float cv[8], sv[8];
#pragma unroll
        for (int jl = 0; jl < 8; ++jl) {
            int l = tx * 8 + jl;
            cv[jl] = twsA[l][m]; sv[jl] = twsA[l][16 + m];
        }
#pragma unroll
        for (int jo = 0; jo < 8; ++jo)
#pragma unroll
            for (int jl = 0; jl < 8; ++jl) acc[jo][jl] += orv[jo] * cv[jl] + oiv[jo] * sv[jl];
    }
#pragma unroll
    for (int jo = 0; jo < 8; ++jo) {
        int o = ty * 8 + jo;
        float v[8];
#pragma unroll
        for (int jl = 0; jl < 8; ++jl) {
            float x = acc[jo][jl] + bv[jo];
            v[jl] = GELU ? gelu_f(x) : x;
        }
        *(float4*)&A[o * 128 + tx * 8]     = make_float4(v[0], v[1], v[2], v[3]);
        *(float4*)&A[o * 128 + tx * 8 + 4] = make_float4(v[4], v[5], v[6], v[7]);
    }
}

// fc1 split-K: 128x128 tile, 8x8/thread, split-K=64 (chunk 256)
__global__ __launch_bounds__(256) void k_fc12(const float* fc1w, float* ws) {
    __shared__ float as_[32][132];
    __shared__ float ws_[32][132];
    int t = threadIdx.x;
    int b0 = blockIdx.x * 128;
    int kz = blockIdx.y;
    const float* A = ws + OFF_A;
    int tm = t >> 4, tn = t & 15;
    float acc[8][8];
#pragma unroll
    for (int jb = 0; jb < 8; ++jb)
#pragma unroll
        for (int jc = 0; jc < 8; ++jc) acc[jb][jc] = 0.f;
    for (int ks = 0; ks < 8; ++ks) {
        int k0 = kz * 256 + ks * 32;
        __syncthreads();
#pragma unroll
        for (int q = 0; q < 4; ++q) {
            int idx = q * 256 + t;
            int r = idx >> 3, kq = idx & 7;
            float4 v = *(const float4*)&A[(b0 + r) * 16384 + k0 + 4 * kq];
            as_[4*kq+0][r] = v.x; as_[4*kq+1][r] = v.y; as_[4*kq+2][r] = v.z; as_[4*kq+3][r] = v.w;
        }
#pragma unroll
        for (int q = 0; q < 4; ++q) {
            int idx = q * 256 + t;
            int c = idx >> 3, kq = idx & 7;
            float4 v = *(const float4*)&fc1w[c * 16384 + k0 + 4 * kq];
            ws_[4*kq+0][c] = v.x; ws_[4*kq+1][c] = v.y; ws_[4*kq+2][c] = v.z; ws_[4*kq+3][c] = v.w;
        }
        __syncthreads();
#pragma unroll 4
        for (int kk = 0; kk < 32; ++kk) {
            float4 a0 = *(const float4*)&as_[kk][tm * 8];
            float4 a1 = *(const float4*)&as_[kk][tm * 8 + 4];
            float4 w0 = *(const float4*)&ws_[kk][tn * 8];
            float4 w1 = *(const float4*)&ws_[kk][tn * 8 + 4];
            float av[8] = {a0.x,a0.y,a0.z,a0.w,a1.x,a1.y,a1.z,a1.w};
            float wv[8] = {w0.x,w0.y,w0.z,w0.w,w1.x,w1.y,w1.z,w1.w};
#pragma unroll
            for (int jb = 0; jb < 8; ++jb)
#pragma unroll
                for (int jc = 0; jc < 8; ++jc) acc[jb][jc] += av[jb] * wv[jc];
        }
    }
    float* hp = ws + OFF_HP + kz * 262144;
#pragma unroll
    for (int jb = 0; jb < 8; ++jb) {
        int b = b0 + tm * 8 + jb;
        *(float4*)&hp[b * 128 + tn * 8]     = make_float4(acc[jb][0], acc[jb][1], acc[jb][2], acc[jb][3]);
        *(float4*)&hp[b * 128 + tn * 8 + 4] = make_float4(acc[jb][4], acc[jb][5], acc[jb][6], acc[jb][7]);
    }
}

__global__ __launch_bounds__(256) void k_fc2(const float* fc1b, const float* fc2w, const float* fc2b,
                                             float* ws, float* out) {
    __shared__ float hs[8][128];
    __shared__ float w2s[64][129];
    int t = threadIdx.x;
    int b0 = blockIdx.x * 8;
    const float* hp = ws + OFF_HP;
#pragma unroll
    for (int q = 0; q < 4; ++q) {
        int idx = q * 256 + t;
        int bb = idx >> 7, c = idx & 127;
        float s = fc1b[c];
#pragma unroll 8
        for (int kz = 0; kz < 64; ++kz) s += hp[kz * 262144 + (b0 + bb) * 128 + c];
        hs[bb][c] = gelu_f(s);
    }
#pragma unroll
    for (int q = 0; q < 32; ++q) {
        int idx = q * 256 + t;
        w2s[idx >> 7][idx & 127] = fc2w[idx];
    }
    __syncthreads();
#pragma unroll
    for (int q = 0; q < 2; ++q) {
        int idx = q * 256 + t;
        int bb = idx >> 6, u = idx & 63;
        float acc = fc2b[u];
#pragma unroll 8
        for (int c = 0; c < 128; ++c) acc += hs[bb][c] * w2s[u][c];
        out[(b0 + bb) * 64 + u] = acc;
    }
}

extern "C" void kernel_launch(void* const* d_in, const int* in_sizes, int n_in,
                              void* d_out, int out_size, void* d_ws, size_t ws_size,
                              hipStream_t stream) {
    const float* X1   = (const float*)d_in[0];
    const float* fc0w = (const float*)d_in[1];
    const float* fc0b = (const float*)d_in[2];
    const float* s0r  = (const float*)d_in[3];
    const float* s0i  = (const float*)d_in[4];
    const float* s1r  = (const float*)d_in[5];
    const float* s1i  = (const float*)d_in[6];
    const float* s2r  = (const float*)d_in[7];
    const float* s2i  = (const float*)d_in[8];
    const float* s3r  = (const float*)d_in[9];
    const float* s3i  = (const float*)d_in[10];
    const float* w0w  = (const float*)d_in[11];
    const float* w0b  = (const float*)d_in[12];
    const float* w1w  = (const float*)d_in[13];
    const float* w1b  = (const float*)d_in[14];
    const float* w2w  = (const float*)d_in[15];
    const float* w2b  = (const float*)d_in[16];
    const float* w3w  = (const float*)d_in[17];
    const float* w3b  = (const float*)d_in[18];
    const float* fc1w = (const float*)d_in[19];
    const float* fc1b = (const float*)d_in[20];
    const float* fc2w = (const float*)d_in[21];
    const float* fc2b = (const float*)d_in[22];
    float* ws  = (float*)d_ws;
    float* out = (float*)d_out;

    k_setup<<<dim3(16), dim3(256), 0, stream>>>(ws);
    k_transpose<<<dim3(3072), dim3(256), 0, stream>>>(s1r, s1i, s2r, s2i, s3r, s3i, ws);
    k_fc0<<<dim3(128), dim3(256), 0, stream>>>(X1, fc0w, fc0b, ws);
    k_layer0<<<dim3(2048), dim3(256), 0, stream>>>(s0r, s0i, w0w, w0b, ws);

    const float* pww[3] = {w1w, w2w, w3w};
    const float* pwb[3] = {w1b, w2b, w3b};
    for (int lay = 0; lay < 3; ++lay) {
        k_dft<<<dim3(512), dim3(256), 0, stream>>>(ws);
        k_modemix<<<dim3(32, 16), dim3(256), 0, stream>>>(lay, ws);
        if (lay < 2)
            k_layerB<1><<<dim3(2048), dim3(256), 0, stream>>>(pww[lay], pwb[lay], ws);
        else
            k_layerB<0><<<dim3(2048), dim3(256), 0, stream>>>(pww[lay], pwb[lay], ws);
    }

    k_fc12<<<dim3(16, 64), dim3(256), 0, stream>>>(fc1w, ws);
    k_fc2<<<dim3(256), dim3(256), 0, stream>>>(fc1b, fc2w, fc2b, ws, out);
}